// Round 13
// baseline (440.957 us; speedup 1.0000x reference)
//
#include <hip/hip_runtime.h>
#include <math.h>

#define HID 128
#define NN 512
#define NNODE 1024
#define CUTR 10.0f

// ---- ws layout, float offsets
#define WS_A    0            // [1024][256] fp32  (A_i + bias + const-angular row)
#define WS_BMF  262144       // BmT fp32 [2][256][512] (c-major, j inner)
#define WS_N1T  786432       // nw1^T fp32 [128][256]
#define WS_N2T  819200       // nw2^T fp32 [128][128]
#define WS_B12  835584       // [128] fp32  eb2 @ cw1
// ---- ws layout, ushort offsets (floats end at 835712 -> ushort 1671424)
#define SE2T_OFF  1671424                 // ew2^T bf16 [128][256]
#define SW12T_OFF (SE2T_OFF + 32768)      // (ew2@cw1)^T bf16 [128][256]
#define SW1G_OFF  (SW12T_OFF + 32768)     // W1g^T bf16 [256][16]

// ---- out layout (float offsets)
#define OUT_POS 131072
#define OUT_VEL 133120

typedef __attribute__((ext_vector_type(8)))  short short8;
typedef __attribute__((ext_vector_type(8)))  __bf16 bf16x8;
typedef __attribute__((ext_vector_type(16))) float float16;

__device__ __forceinline__ float silu_f(float x) {
  return x * __builtin_amdgcn_rcpf(1.f + __expf(-x));
}
__device__ __forceinline__ short f2bf(float x) {
  return __builtin_bit_cast(short, (__bf16)x);   // native v_cvt (RNE)
}
__device__ __forceinline__ float bf2f(unsigned short u) {
  union { unsigned u; float f; } v; v.u = ((unsigned)u) << 16;
  return v.f;
}
__device__ __forceinline__ bf16x8 as_bf(short8 s) {
  return __builtin_bit_cast(bf16x8, s);
}
__device__ __forceinline__ float16 zero16() {
  float16 z;
#pragma unroll
  for (int r = 0; r < 16; ++r) z[r] = 0.f;
  return z;
}

// ---------------------------------------------------------------- K01
// blocks [0,256): A (fp32) + BmT (fp32, c-major) for 4 nodes each.
// blocks [256,721): weight prep — W12^T, ew2^T, W1g^T, B12, nw1^T, nw2^T.
__global__ __launch_bounds__(256)
void k01_prep(const float* __restrict__ h, const float* __restrict__ ew1,
              const float* __restrict__ eb1, const float* __restrict__ ew2,
              const float* __restrict__ cw1, const float* __restrict__ eb2,
              const float* __restrict__ nw1, const float* __restrict__ nw2,
              float* __restrict__ ws, unsigned short* __restrict__ wsU) {
  int blk = blockIdx.x;
  int t = threadIdx.x;
  if (blk < 256) {
    __shared__ float sh_h[4][HID];
    int base = blk * 4;
    for (int idx = t; idx < 4*HID; idx += 256)
      sh_h[idx >> 7][idx & 127] = h[base*HID + idx];
    __syncthreads();
    int c = t;
    float bias = eb1[c] + ew1[264*256 + c];
    float a0=bias, a1=bias, a2=bias, a3=bias;
    float b0=0.f, b1=0.f, b2=0.f, b3=0.f;
#pragma unroll 4
    for (int k = 0; k < HID; ++k) {
      float ea = ew1[k*256 + c];
      float eb = ew1[(128+k)*256 + c];
      float h0 = sh_h[0][k], h1 = sh_h[1][k], h2 = sh_h[2][k], h3 = sh_h[3][k];
      a0 += h0*ea; b0 += h0*eb;
      a1 += h1*ea; b1 += h1*eb;
      a2 += h2*ea; b2 += h2*eb;
      a3 += h3*ea; b3 += h3*eb;
    }
    float av[4] = {a0,a1,a2,a3};
    float bv[4] = {b0,b1,b2,b3};
#pragma unroll
    for (int n = 0; n < 4; ++n) {
      int node = base + n;
      ws[WS_A + node*256 + c] = av[n];
      int b = node >> 9, j = node & 511;
      ws[WS_BMF + b*131072 + c*512 + j] = bv[n];
    }
  } else {
    int idx = (blk - 256) * 256 + t;
    if (idx < 32768) {
      // W12T[d][cp] = sum_c ew2[cp][c] * cw1[c][d]
      int d = idx & 127, cp = idx >> 7;
      float s = 0.f;
#pragma unroll 4
      for (int c = 0; c < 128; ++c) s += ew2[cp*128 + c] * cw1[c*128 + d];
      wsU[SW12T_OFF + d*256 + cp] = (unsigned short)f2bf(s);
    } else if (idx < 65536) {
      int i2 = idx - 32768; int c = i2 >> 8, k = i2 & 255;
      wsU[SE2T_OFF + c*256 + k] = (unsigned short)f2bf(ew2[k*HID + c]);
    } else if (idx < 69632) {
      int i3 = idx - 65536; int c = i3 >> 4, f = i3 & 15;
      int row = (f < 8) ? (256 + f) : (257 + f);
      wsU[SW1G_OFF + c*16 + f] = (unsigned short)f2bf(ew1[row*256 + c]);
    } else if (idx < 69760) {
      int d = idx - 69632;
      float s = 0.f;
#pragma unroll 4
      for (int c = 0; c < 128; ++c) s += eb2[c] * cw1[c*128 + d];
      ws[WS_B12 + d] = s;
    } else if (idx < 102528) {
      int i4 = idx - 69760; int d = i4 >> 8, k = i4 & 255;
      ws[WS_N1T + d*256 + k] = nw1[k*HID + d];
    } else if (idx < 118912) {
      int i5 = idx - 102528; int d = i5 >> 7, k = i5 & 127;
      ws[WS_N2T + d*128 + k] = nw2[k*HID + d];
    }
  }
}

// ---------------------------------------------------------------- K3
// One block per (b,i); 4 waves. r12 fused pipeline with two VALU diets:
// (1) cut16[16] built once per chunk (16 shfl), reused for hacc in both
//     ct slices AND the epilogue (was 48 shfl for cut);
// (2) BmT fp32 c-major: C-init = float4 loads + add (no bf16 unpack).
// Epilogue precedes phase1(k+1) in source so one cut16 buffer suffices;
// same barrier region — scheduler still interleaves with the GEMM.
__global__ __launch_bounds__(256)
void k3_edge(const float* __restrict__ pos, const float* __restrict__ vel,
             const float* __restrict__ h,
             const float* __restrict__ cb1, const float* __restrict__ cw2,
             const float* __restrict__ cb2, const float* __restrict__ eb2,
             const float* __restrict__ nb1, const float* __restrict__ nb2,
             const float* __restrict__ lng, const float* __restrict__ lnb,
             float* __restrict__ ws, float* __restrict__ out) {
  const short* wsS = (const short*)ws;
  __shared__ __align__(16) short shH[2][32*256];  // bf16, xor-swizzled, double-buffered
  __shared__ float shsum[256];
  __shared__ float shred[12];

  const int t = threadIdx.x;
  const int w = t >> 6, l = t & 63, lo = l & 31, hl = l >> 5, hl4 = hl * 4;
  const int node = blockIdx.x;
  const int b = node >> 9;
  const int bN = b * NN;

  const bf16x8 wg0 = as_bf(*(const short8*)(wsS + SW1G_OFF + (64*w + lo)*16 + hl*8));
  const bf16x8 wg1 = as_bf(*(const short8*)(wsS + SW1G_OFF + (64*w + 32 + lo)*16 + hl*8));

  const float a0   = ws[WS_A + node*256 + 64*w + lo];
  const float a1   = ws[WS_A + node*256 + 64*w + 32 + lo];
  const float cb1v = cb1[32*w + lo];
  const float c2v  = cw2[32*w + lo];
  const float b12v = ws[WS_B12 + 32*w + lo];
  const float cb2c = cb2[0] * (1.f/128.f);
  const float pix  = pos[node*2], piy = pos[node*2+1];

  float hs0 = 0.f, hs1 = 0.f;    // hsum partials for cols 64w+lo, 64w+32+lo
  float cs = 0.f;                // sum_j cut_j (per-lane over own j's)
  float S = 0.f, SX = 0.f, SY = 0.f;
  float cutv, pjx, pjy;
  float cutv_n, pjx_n, pjy_n;
  float cut16[16];               // cut[row(r)] for this chunk (built in phase1)

  auto phase1 = [&](int jbw, int bufsel) {
    const int jb = jbw & (NN - 1);
    const int jn = bN + jb + lo;
    pjx_n = pos[2*jn]; pjy_n = pos[2*jn+1];
    const float dx = pix - pjx_n, dy = piy - pjy_n;
    const float d = sqrtf(dx*dx + dy*dy);
    cutv_n = (d < CUTR) ? 0.5f*(__cosf((float)M_PI*(1.f/CUTR)*d) + 1.f) : 0.f;
    if (jbw >= NN) cutv_n = 0.f;
    // broadcast cut[row] once; reused by hacc (both cts) and next epilogue
#pragma unroll
    for (int r = 0; r < 16; ++r)
      cut16[r] = __shfl(cutv_n, (r&3) + 8*(r>>2) + hl4, 32);
    short8 gs;
    if (hl == 0) {
#pragma unroll
      for (int k = 0; k < 8; ++k) {
        float ctr = (CUTR * (float)k) / 7.0f;
        float tt = (d - ctr) * 0.8f;
        gs[k] = f2bf(__expf(-tt*tt));
      }
    } else {
      float invd = __builtin_amdgcn_rcpf(d + 1e-8f);
      float c1 = dx * invd, s1 = dy * invd;
      if (d == 0.f) { c1 = 1.f; s1 = 0.f; }
      float c2 = c1*c1 - s1*s1, s2 = 2.f*s1*c1;
      float c3 = c2*c1 - s2*s1, s3 = s2*c1 + c2*s1;
      float c4 = c3*c1 - s3*s1, s4 = s3*c1 + c3*s1;
      gs[0]=f2bf(c1); gs[1]=f2bf(c2); gs[2]=f2bf(c3); gs[3]=f2bf(c4);
      gs[4]=f2bf(s1); gs[5]=f2bf(s2); gs[6]=f2bf(s3); gs[7]=f2bf(s4);
    }
    const bf16x8 gf = as_bf(gs);
    short* shb = &shH[bufsel][0];
#pragma unroll
    for (int ct = 0; ct < 2; ++ct) {
      const int colg = 64*w + 32*ct + lo;
      const float av = ct ? a1 : a0;
      const float* bt = ws + WS_BMF + b*131072 + colg*512 + jb + hl4;
      float16 ci;
#pragma unroll
      for (int g = 0; g < 4; ++g) {
        float4 v4 = *(const float4*)(bt + 8*g);
        ci[4*g+0] = v4.x + av;
        ci[4*g+1] = v4.y + av;
        ci[4*g+2] = v4.z + av;
        ci[4*g+3] = v4.w + av;
      }
      float16 hp = __builtin_amdgcn_mfma_f32_32x32x16_bf16(gf, ct ? wg1 : wg0, ci, 0, 0, 0);
      const int ck = colg >> 3;
      float hacc = 0.f;
#pragma unroll
      for (int r = 0; r < 16; ++r) {
        int row = (r&3) + 8*(r>>2) + hl4;
        float sv = silu_f(hp[r]);
        hacc += cut16[r] * sv;
        shb[row*256 + (((ck ^ row) & 31) << 3) + (colg & 7)] = f2bf(sv);
      }
      if (ct) hs1 += hacc; else hs0 += hacc;
    }
  };

  // prologue: chunk 0 -> buf 0
  phase1(0, 0);
  cutv = cutv_n; pjx = pjx_n; pjy = pjy_n;
  __syncthreads();

  for (int k = 0; k < 16; ++k) {
    cs += cutv;

    // ---- GEMM: H @ W12 (K=256), weights streamed from L1/L2
    float16 acc2 = zero16();
    {
      const short* wp = wsS + SW12T_OFF + (32*w + lo)*256 + hl*8;
      const short* shb = &shH[k & 1][0];
#pragma unroll 4
      for (int s = 0; s < 16; ++s) {
        bf16x8 wv = as_bf(*(const short8*)(wp + 16*s));
        const int ck = 2*s + hl;
        bf16x8 af = as_bf(*(const short8*)(shb + lo*256 + (((ck ^ lo) & 31) << 3)));
        acc2 = __builtin_amdgcn_mfma_f32_32x32x16_bf16(af, wv, acc2, 0, 0, 0);
      }
    }

    // ---- epilogue (chunk k): c1 = cut*(acc2+B12)+cb1; p = silu(c1)*cw2 + cb2/128
    // uses cut16 (built for chunk k) before phase1 overwrites it
#pragma unroll
    for (int r = 0; r < 16; ++r) {
      int row = (r&3) + 8*(r>>2) + hl4;
      float p = silu_f(cut16[r] * (acc2[r] + b12v) + cb1v) * c2v + cb2c;
      S += p;
      SX += p * __shfl(pjx, row, 32);
      SY += p * __shfl(pjy, row, 32);
    }

    // ---- phase1 for chunk k+1 -> other buffer (overlaps the GEMM/epilogue)
    phase1((k + 1) * 32, (k + 1) & 1);

    cutv = cutv_n; pjx = pjx_n; pjy = pjy_n;
    __syncthreads();   // buf(k+1) writes complete; buf(k) reads complete
  }

  // ---- hsum: merge hl halves, stage to LDS
  hs0 += __shfl_xor(hs0, 32);
  hs1 += __shfl_xor(hs1, 32);
  if (hl == 0) {
    shsum[64*w + lo] = hs0;
    shsum[64*w + 32 + lo] = hs1;
  }

  // ---- cutsum: butterfly within 32 (identical across halves/waves)
  float cutsum = cs;
#pragma unroll
  for (int m = 1; m < 32; m <<= 1) cutsum += __shfl_xor(cutsum, m, 32);

  // ---- S/SX/SY wave reduce
#pragma unroll
  for (int off = 32; off > 0; off >>= 1) {
    S  += __shfl_xor(S, off);
    SX += __shfl_xor(SX, off);
    SY += __shfl_xor(SY, off);
  }
  if (l == 0) { shred[w] = S; shred[4 + w] = SX; shred[8 + w] = SY; }
  __syncthreads();

  // ================= fused node tail (all 256 threads) =================
  float* shIn  = (float*)&shH[0][0];    // 256 floats
  float* shHid = shIn + 256;            // 128 floats
  float* pm    = (float*)&shH[1][0];    // 256 float partials
  const int d  = t & 127, half = t >> 7;

  // ---- msg GEMV partials: pm[t] = sum over half of c' of hsum*ew2T
  {
    const short* er = wsS + SE2T_OFF + d*256 + half*128;
    const float* ss = shsum + half*128;
    float m = 0.f;
#pragma unroll 4
    for (int kk = 0; kk < 16; ++kk) {
      short8 v = *(const short8*)(er + kk*8);
      const float4 s0 = *(const float4*)(ss + kk*8);
      const float4 s1 = *(const float4*)(ss + kk*8 + 4);
      m += bf2f((unsigned short)v[0])*s0.x + bf2f((unsigned short)v[1])*s0.y
         + bf2f((unsigned short)v[2])*s0.z + bf2f((unsigned short)v[3])*s0.w
         + bf2f((unsigned short)v[4])*s1.x + bf2f((unsigned short)v[5])*s1.y
         + bf2f((unsigned short)v[6])*s1.z + bf2f((unsigned short)v[7])*s1.w;
    }
    pm[t] = m;
  }
  if (t == 0) {
    float St  = shred[0] + shred[1] + shred[2]  + shred[3];
    float SXt = shred[4] + shred[5] + shred[6]  + shred[7];
    float SYt = shred[8] + shred[9] + shred[10] + shred[11];
    float updx = pix*St - SXt, updy = piy*St - SYt;
    out[OUT_POS + node*2+0] = pix + updx;
    out[OUT_POS + node*2+1] = piy + updy;
    out[OUT_VEL + node*2+0] = vel[node*2+0] + 0.1f*updx;
    out[OUT_VEL + node*2+1] = vel[node*2+1] + 0.1f*updy;
  }
  __syncthreads();

  // ---- assemble node input: h | msg
  if (t < HID) {
    shIn[t]       = h[node*HID + t];
    shIn[HID + t] = pm[t] + pm[t + 128] + eb2[t] * cutsum;
  }
  __syncthreads();

  // ---- MLP layer 1: pm[t] = sum over half-k of shIn*nw1T (float4 loads)
  {
    const float* wr = ws + WS_N1T + d*256 + half*128;
    const float* si = shIn + half*128;
    float s = 0.f;
#pragma unroll 4
    for (int kk = 0; kk < 32; ++kk) {
      float4 wv = *(const float4*)(wr + kk*4);
      float4 iv = *(const float4*)(si + kk*4);
      s += wv.x*iv.x + wv.y*iv.y + wv.z*iv.z + wv.w*iv.w;
    }
    __syncthreads();   // pm reuse: msg reads done
    pm[t] = s;
  }
  __syncthreads();
  if (t < HID) shHid[t] = silu_f(nb1[t] + pm[t] + pm[t + 128]);
  __syncthreads();

  // ---- MLP layer 2 partials
  {
    const float* wr = ws + WS_N2T + d*128 + half*64;
    const float* si = shHid + half*64;
    float s = 0.f;
#pragma unroll 4
    for (int kk = 0; kk < 16; ++kk) {
      float4 wv = *(const float4*)(wr + kk*4);
      float4 iv = *(const float4*)(si + kk*4);
      s += wv.x*iv.x + wv.y*iv.y + wv.z*iv.z + wv.w*iv.w;
    }
    pm[t] = s;
  }
  __syncthreads();

  // ---- residual + LayerNorm (t < 128)
  float x = 0.f;
  if (t < HID) {
    x = shIn[t] + nb2[t] + pm[t] + pm[t + 128];
    float v1 = x, v2 = x*x;
#pragma unroll
    for (int off = 32; off > 0; off >>= 1) {
      v1 += __shfl_down(v1, off);
      v2 += __shfl_down(v2, off);
    }
    if (l == 0) { shred[w] = v1; shred[2 + w] = v2; }
  }
  __syncthreads();
  if (t < HID) {
    float mu  = (shred[0] + shred[1]) * (1.f/HID);
    float var = (shred[2] + shred[3]) * (1.f/HID) - mu*mu;
    float inv = 1.f / sqrtf(var + 1e-5f);
    out[node*HID + t] = (x - mu) * inv * lng[t] + lnb[t];
  }
}

// ---------------------------------------------------------------- launch
extern "C" void kernel_launch(void* const* d_in, const int* in_sizes, int n_in,
                              void* d_out, int out_size, void* d_ws, size_t ws_size,
                              hipStream_t stream) {
  (void)in_sizes; (void)n_in; (void)out_size; (void)ws_size;
  const float* h   = (const float*)d_in[0];
  const float* pos = (const float*)d_in[1];
  const float* vel = (const float*)d_in[2];
  const float* ew1 = (const float*)d_in[3];
  const float* eb1 = (const float*)d_in[4];
  const float* ew2 = (const float*)d_in[5];
  const float* eb2 = (const float*)d_in[6];
  const float* cw1 = (const float*)d_in[7];
  const float* cb1 = (const float*)d_in[8];
  const float* cw2 = (const float*)d_in[9];
  const float* cb2 = (const float*)d_in[10];
  const float* nw1 = (const float*)d_in[11];
  const float* nb1 = (const float*)d_in[12];
  const float* nw2 = (const float*)d_in[13];
  const float* nb2 = (const float*)d_in[14];
  const float* lng = (const float*)d_in[15];
  const float* lnb = (const float*)d_in[16];
  float* out = (float*)d_out;
  float* ws  = (float*)d_ws;
  unsigned short* wsU = (unsigned short*)d_ws;

  hipLaunchKernelGGL(k01_prep, dim3(721), dim3(256), 0, stream,
                     h, ew1, eb1, ew2, cw1, eb2, nw1, nw2, ws, wsU);
  hipLaunchKernelGGL(k3_edge, dim3(NNODE), dim3(256), 0, stream,
                     pos, vel, h, cb1, cw2, cb2, eb2,
                     nb1, nb2, lng, lnb, ws, out);
}

// Round 14
// 339.497 us; speedup vs baseline: 1.2989x; 1.2989x over previous
//
#include <hip/hip_runtime.h>
#include <math.h>

#define HID 128
#define NN 512
#define NNODE 1024
#define CUTR 10.0f

// ---- ws layout, float offsets
#define WS_A    0            // [1024][256] fp32  (A_i + bias + const-angular row)
#define WS_N1T  262144       // nw1^T fp32 [128][256]
#define WS_N2T  294912       // nw2^T fp32 [128][128]
#define WS_B12  393216       // [128] fp32  eb2 @ cw1
// ---- ws layout, ushort offsets
#define SBMT_OFF  786688                  // BmT bf16 [2][256][512]  (c-major, j inner)
#define SE2T_OFF  (SBMT_OFF + 262144)     // ew2^T bf16 [128][256]
#define SW12T_OFF (SE2T_OFF + 32768)      // (ew2@cw1)^T bf16 [128][256]
#define SW1G_OFF  (SW12T_OFF + 32768)     // W1g^T bf16 [256][16]

// ---- out layout (float offsets)
#define OUT_POS 131072
#define OUT_VEL 133120

typedef __attribute__((ext_vector_type(8)))  short short8;
typedef __attribute__((ext_vector_type(4)))  unsigned short ushort4v;
typedef __attribute__((ext_vector_type(8)))  __bf16 bf16x8;
typedef __attribute__((ext_vector_type(16))) float float16;

__device__ __forceinline__ float silu_f(float x) {
  return x * __builtin_amdgcn_rcpf(1.f + __expf(-x));
}
__device__ __forceinline__ short f2bf(float x) {
  return __builtin_bit_cast(short, (__bf16)x);   // native v_cvt (RNE)
}
__device__ __forceinline__ float bf2f(unsigned short u) {
  union { unsigned u; float f; } v; v.u = ((unsigned)u) << 16;
  return v.f;
}
__device__ __forceinline__ bf16x8 as_bf(short8 s) {
  return __builtin_bit_cast(bf16x8, s);
}
__device__ __forceinline__ float16 zero16() {
  float16 z;
#pragma unroll
  for (int r = 0; r < 16; ++r) z[r] = 0.f;
  return z;
}

// ---------------------------------------------------------------- K01
// blocks [0,256): A (fp32) + BmT (bf16) for 4 nodes each — ew1 row loaded
// once per 4 nodes (4x less L2 traffic than 1-node blocks).
// blocks [256,721): weight prep — W12^T, ew2^T, W1g^T, B12, nw1^T, nw2^T.
__global__ __launch_bounds__(256)
void k01_prep(const float* __restrict__ h, const float* __restrict__ ew1,
              const float* __restrict__ eb1, const float* __restrict__ ew2,
              const float* __restrict__ cw1, const float* __restrict__ eb2,
              const float* __restrict__ nw1, const float* __restrict__ nw2,
              float* __restrict__ ws, unsigned short* __restrict__ wsU) {
  int blk = blockIdx.x;
  int t = threadIdx.x;
  if (blk < 256) {
    __shared__ float sh_h[4][HID];
    int base = blk * 4;
    for (int idx = t; idx < 4*HID; idx += 256)
      sh_h[idx >> 7][idx & 127] = h[base*HID + idx];
    __syncthreads();
    int c = t;
    float bias = eb1[c] + ew1[264*256 + c];
    float a0=bias, a1=bias, a2=bias, a3=bias;
    float b0=0.f, b1=0.f, b2=0.f, b3=0.f;
#pragma unroll 4
    for (int k = 0; k < HID; ++k) {
      float ea = ew1[k*256 + c];
      float eb = ew1[(128+k)*256 + c];
      float h0 = sh_h[0][k], h1 = sh_h[1][k], h2 = sh_h[2][k], h3 = sh_h[3][k];
      a0 += h0*ea; b0 += h0*eb;
      a1 += h1*ea; b1 += h1*eb;
      a2 += h2*ea; b2 += h2*eb;
      a3 += h3*ea; b3 += h3*eb;
    }
    float av[4] = {a0,a1,a2,a3};
    float bv[4] = {b0,b1,b2,b3};
#pragma unroll
    for (int n = 0; n < 4; ++n) {
      int node = base + n;
      ws[WS_A + node*256 + c] = av[n];
      int b = node >> 9, j = node & 511;
      wsU[SBMT_OFF + b*131072 + c*512 + j] = (unsigned short)f2bf(bv[n]);
    }
  } else {
    int idx = (blk - 256) * 256 + t;
    if (idx < 32768) {
      // W12T[d][cp] = sum_c ew2[cp][c] * cw1[c][d]
      int d = idx & 127, cp = idx >> 7;
      float s = 0.f;
#pragma unroll 4
      for (int c = 0; c < 128; ++c) s += ew2[cp*128 + c] * cw1[c*128 + d];
      wsU[SW12T_OFF + d*256 + cp] = (unsigned short)f2bf(s);
    } else if (idx < 65536) {
      int i2 = idx - 32768; int c = i2 >> 8, k = i2 & 255;
      wsU[SE2T_OFF + c*256 + k] = (unsigned short)f2bf(ew2[k*HID + c]);
    } else if (idx < 69632) {
      int i3 = idx - 65536; int c = i3 >> 4, f = i3 & 15;
      int row = (f < 8) ? (256 + f) : (257 + f);
      wsU[SW1G_OFF + c*16 + f] = (unsigned short)f2bf(ew1[row*256 + c]);
    } else if (idx < 69760) {
      int d = idx - 69632;
      float s = 0.f;
#pragma unroll 4
      for (int c = 0; c < 128; ++c) s += eb2[c] * cw1[c*128 + d];
      ws[WS_B12 + d] = s;
    } else if (idx < 102528) {
      int i4 = idx - 69760; int d = i4 >> 8, k = i4 & 255;
      ws[WS_N1T + d*256 + k] = nw1[k*HID + d];
    } else if (idx < 118912) {
      int i5 = idx - 102528; int d = i5 >> 7, k = i5 & 127;
      ws[WS_N2T + d*128 + k] = nw2[k*HID + d];
    }
  }
}

// ---------------------------------------------------------------- K3
// One block per (b,i); 4 waves. r9 fused edge pipeline (best-measured)
// + vectorized node tail. REGISTER LAW (r5/r7/r8/r13): this config is at
// the 2-waves/SIMD boundary (~220 unified regs, VGPR_Count 124). ANY
// added per-thread state (arrays, fp32 staging, pipeline regs) drops to
// 1 wave/SIMD and costs ~35%. Do not add registers here.
__global__ __launch_bounds__(256)
void k3_edge(const float* __restrict__ pos, const float* __restrict__ vel,
             const float* __restrict__ h,
             const float* __restrict__ cb1, const float* __restrict__ cw2,
             const float* __restrict__ cb2, const float* __restrict__ eb2,
             const float* __restrict__ nb1, const float* __restrict__ nb2,
             const float* __restrict__ lng, const float* __restrict__ lnb,
             float* __restrict__ ws, float* __restrict__ out) {
  const short* wsS = (const short*)ws;
  const unsigned short* wsU = (const unsigned short*)ws;
  __shared__ __align__(16) short shH[2][32*256];  // bf16, xor-swizzled, double-buffered
  __shared__ float shsum[256];
  __shared__ float shred[12];

  const int t = threadIdx.x;
  const int w = t >> 6, l = t & 63, lo = l & 31, hl = l >> 5, hl4 = hl * 4;
  const int node = blockIdx.x;
  const int b = node >> 9;
  const int bN = b * NN;

  const bf16x8 wg0 = as_bf(*(const short8*)(wsS + SW1G_OFF + (64*w + lo)*16 + hl*8));
  const bf16x8 wg1 = as_bf(*(const short8*)(wsS + SW1G_OFF + (64*w + 32 + lo)*16 + hl*8));

  const float a0   = ws[WS_A + node*256 + 64*w + lo];
  const float a1   = ws[WS_A + node*256 + 64*w + 32 + lo];
  const float cb1v = cb1[32*w + lo];
  const float c2v  = cw2[32*w + lo];
  const float b12v = ws[WS_B12 + 32*w + lo];
  const float cb2c = cb2[0] * (1.f/128.f);
  const float pix  = pos[node*2], piy = pos[node*2+1];

  float hs0 = 0.f, hs1 = 0.f;    // hsum partials for cols 64w+lo, 64w+32+lo
  float cs = 0.f;                // sum_j cut_j (per-lane over own j's)
  float S = 0.f, SX = 0.f, SY = 0.f;
  float cutv, pjx, pjy;
  float cutv_n, pjx_n, pjy_n;

  auto phase1 = [&](int jbw, int bufsel) {
    const int jb = jbw & (NN - 1);
    const int jn = bN + jb + lo;
    pjx_n = pos[2*jn]; pjy_n = pos[2*jn+1];
    const float dx = pix - pjx_n, dy = piy - pjy_n;
    const float d = sqrtf(dx*dx + dy*dy);
    cutv_n = (d < CUTR) ? 0.5f*(__cosf((float)M_PI*(1.f/CUTR)*d) + 1.f) : 0.f;
    if (jbw >= NN) cutv_n = 0.f;
    short8 gs;
    if (hl == 0) {
#pragma unroll
      for (int k = 0; k < 8; ++k) {
        float ctr = (CUTR * (float)k) / 7.0f;
        float tt = (d - ctr) * 0.8f;
        gs[k] = f2bf(__expf(-tt*tt));
      }
    } else {
      float invd = __builtin_amdgcn_rcpf(d + 1e-8f);
      float c1 = dx * invd, s1 = dy * invd;
      if (d == 0.f) { c1 = 1.f; s1 = 0.f; }
      float c2 = c1*c1 - s1*s1, s2 = 2.f*s1*c1;
      float c3 = c2*c1 - s2*s1, s3 = s2*c1 + c2*s1;
      float c4 = c3*c1 - s3*s1, s4 = s3*c1 + c3*s1;
      gs[0]=f2bf(c1); gs[1]=f2bf(c2); gs[2]=f2bf(c3); gs[3]=f2bf(c4);
      gs[4]=f2bf(s1); gs[5]=f2bf(s2); gs[6]=f2bf(s3); gs[7]=f2bf(s4);
    }
    const bf16x8 gf = as_bf(gs);
    short* shb = &shH[bufsel][0];
#pragma unroll
    for (int ct = 0; ct < 2; ++ct) {
      const int colg = 64*w + 32*ct + lo;
      const float av = ct ? a1 : a0;
      const unsigned short* bt = wsU + SBMT_OFF + b*131072 + colg*512 + jb + hl4;
      float16 ci;
#pragma unroll
      for (int g = 0; g < 4; ++g) {
        ushort4v v4 = *(const ushort4v*)(bt + 8*g);
        ci[4*g+0] = bf2f(v4[0]) + av;
        ci[4*g+1] = bf2f(v4[1]) + av;
        ci[4*g+2] = bf2f(v4[2]) + av;
        ci[4*g+3] = bf2f(v4[3]) + av;
      }
      float16 hp = __builtin_amdgcn_mfma_f32_32x32x16_bf16(gf, ct ? wg1 : wg0, ci, 0, 0, 0);
      const int ck = colg >> 3;
      float hacc = 0.f;
#pragma unroll
      for (int r = 0; r < 16; ++r) {
        int row = (r&3) + 8*(r>>2) + hl4;
        float sv = silu_f(hp[r]);
        hacc += __shfl(cutv_n, row, 32) * sv;
        shb[row*256 + (((ck ^ row) & 31) << 3) + (colg & 7)] = f2bf(sv);
      }
      if (ct) hs1 += hacc; else hs0 += hacc;
    }
  };

  // prologue: chunk 0 -> buf 0
  phase1(0, 0);
  cutv = cutv_n; pjx = pjx_n; pjy = pjy_n;
  __syncthreads();

  for (int k = 0; k < 16; ++k) {
    cs += cutv;

    // ---- GEMM: H @ W12 (K=256), weights streamed from L1/L2
    float16 acc2 = zero16();
    {
      const short* wp = wsS + SW12T_OFF + (32*w + lo)*256 + hl*8;
      const short* shb = &shH[k & 1][0];
#pragma unroll 4
      for (int s = 0; s < 16; ++s) {
        bf16x8 wv = as_bf(*(const short8*)(wp + 16*s));
        const int ck = 2*s + hl;
        bf16x8 af = as_bf(*(const short8*)(shb + lo*256 + (((ck ^ lo) & 31) << 3)));
        acc2 = __builtin_amdgcn_mfma_f32_32x32x16_bf16(af, wv, acc2, 0, 0, 0);
      }
    }

    // ---- phase1 for chunk k+1 -> other buffer (overlaps the GEMM)
    phase1((k + 1) * 32, (k + 1) & 1);

    // ---- epilogue: c1 = cut*(acc2+B12)+cb1; p = silu(c1)*cw2 + cb2/128
#pragma unroll
    for (int r = 0; r < 16; ++r) {
      int row = (r&3) + 8*(r>>2) + hl4;
      float cr = __shfl(cutv, row, 32);
      float p = silu_f(cr * (acc2[r] + b12v) + cb1v) * c2v + cb2c;
      S += p;
      SX += p * __shfl(pjx, row, 32);
      SY += p * __shfl(pjy, row, 32);
    }

    cutv = cutv_n; pjx = pjx_n; pjy = pjy_n;
    __syncthreads();   // buf(k+1) writes complete; buf(k) reads complete
  }

  // ---- hsum: merge hl halves, stage to LDS
  hs0 += __shfl_xor(hs0, 32);
  hs1 += __shfl_xor(hs1, 32);
  if (hl == 0) {
    shsum[64*w + lo] = hs0;
    shsum[64*w + 32 + lo] = hs1;
  }

  // ---- cutsum: butterfly within 32 (identical across halves/waves)
  float cutsum = cs;
#pragma unroll
  for (int m = 1; m < 32; m <<= 1) cutsum += __shfl_xor(cutsum, m, 32);

  // ---- S/SX/SY wave reduce
#pragma unroll
  for (int off = 32; off > 0; off >>= 1) {
    S  += __shfl_xor(S, off);
    SX += __shfl_xor(SX, off);
    SY += __shfl_xor(SY, off);
  }
  if (l == 0) { shred[w] = S; shred[4 + w] = SX; shred[8 + w] = SY; }
  __syncthreads();

  // ================= fused node tail (all 256 threads) =================
  float* shIn  = (float*)&shH[0][0];    // 256 floats
  float* shHid = shIn + 256;            // 128 floats
  float* pm    = (float*)&shH[1][0];    // 256 float partials
  const int d  = t & 127, half = t >> 7;

  // ---- msg GEMV partials: pm[t] = sum over half of c' of hsum*ew2T
  {
    const short* er = wsS + SE2T_OFF + d*256 + half*128;
    const float* ss = shsum + half*128;
    float m = 0.f;
#pragma unroll 4
    for (int kk = 0; kk < 16; ++kk) {
      short8 v = *(const short8*)(er + kk*8);
      const float4 s0 = *(const float4*)(ss + kk*8);
      const float4 s1 = *(const float4*)(ss + kk*8 + 4);
      m += bf2f((unsigned short)v[0])*s0.x + bf2f((unsigned short)v[1])*s0.y
         + bf2f((unsigned short)v[2])*s0.z + bf2f((unsigned short)v[3])*s0.w
         + bf2f((unsigned short)v[4])*s1.x + bf2f((unsigned short)v[5])*s1.y
         + bf2f((unsigned short)v[6])*s1.z + bf2f((unsigned short)v[7])*s1.w;
    }
    pm[t] = m;
  }
  if (t == 0) {
    float St  = shred[0] + shred[1] + shred[2]  + shred[3];
    float SXt = shred[4] + shred[5] + shred[6]  + shred[7];
    float SYt = shred[8] + shred[9] + shred[10] + shred[11];
    float updx = pix*St - SXt, updy = piy*St - SYt;
    out[OUT_POS + node*2+0] = pix + updx;
    out[OUT_POS + node*2+1] = piy + updy;
    out[OUT_VEL + node*2+0] = vel[node*2+0] + 0.1f*updx;
    out[OUT_VEL + node*2+1] = vel[node*2+1] + 0.1f*updy;
  }
  __syncthreads();

  // ---- assemble node input: h | msg
  if (t < HID) {
    shIn[t]       = h[node*HID + t];
    shIn[HID + t] = pm[t] + pm[t + 128] + eb2[t] * cutsum;
  }
  __syncthreads();

  // ---- MLP layer 1: pm[t] = sum over half-k of shIn*nw1T (float4 loads)
  {
    const float* wr = ws + WS_N1T + d*256 + half*128;
    const float* si = shIn + half*128;
    float s = 0.f;
#pragma unroll 4
    for (int kk = 0; kk < 32; ++kk) {
      float4 wv = *(const float4*)(wr + kk*4);
      float4 iv = *(const float4*)(si + kk*4);
      s += wv.x*iv.x + wv.y*iv.y + wv.z*iv.z + wv.w*iv.w;
    }
    __syncthreads();   // pm reuse: msg reads done
    pm[t] = s;
  }
  __syncthreads();
  if (t < HID) shHid[t] = silu_f(nb1[t] + pm[t] + pm[t + 128]);
  __syncthreads();

  // ---- MLP layer 2 partials
  {
    const float* wr = ws + WS_N2T + d*128 + half*64;
    const float* si = shHid + half*64;
    float s = 0.f;
#pragma unroll 4
    for (int kk = 0; kk < 16; ++kk) {
      float4 wv = *(const float4*)(wr + kk*4);
      float4 iv = *(const float4*)(si + kk*4);
      s += wv.x*iv.x + wv.y*iv.y + wv.z*iv.z + wv.w*iv.w;
    }
    pm[t] = s;
  }
  __syncthreads();

  // ---- residual + LayerNorm (t < 128)
  float x = 0.f;
  if (t < HID) {
    x = shIn[t] + nb2[t] + pm[t] + pm[t + 128];
    float v1 = x, v2 = x*x;
#pragma unroll
    for (int off = 32; off > 0; off >>= 1) {
      v1 += __shfl_down(v1, off);
      v2 += __shfl_down(v2, off);
    }
    if (l == 0) { shred[w] = v1; shred[2 + w] = v2; }
  }
  __syncthreads();
  if (t < HID) {
    float mu  = (shred[0] + shred[1]) * (1.f/HID);
    float var = (shred[2] + shred[3]) * (1.f/HID) - mu*mu;
    float inv = 1.f / sqrtf(var + 1e-5f);
    out[node*HID + t] = (x - mu) * inv * lng[t] + lnb[t];
  }
}

// ---------------------------------------------------------------- launch
extern "C" void kernel_launch(void* const* d_in, const int* in_sizes, int n_in,
                              void* d_out, int out_size, void* d_ws, size_t ws_size,
                              hipStream_t stream) {
  (void)in_sizes; (void)n_in; (void)out_size; (void)ws_size;
  const float* h   = (const float*)d_in[0];
  const float* pos = (const float*)d_in[1];
  const float* vel = (const float*)d_in[2];
  const float* ew1 = (const float*)d_in[3];
  const float* eb1 = (const float*)d_in[4];
  const float* ew2 = (const float*)d_in[5];
  const float* eb2 = (const float*)d_in[6];
  const float* cw1 = (const float*)d_in[7];
  const float* cb1 = (const float*)d_in[8];
  const float* cw2 = (const float*)d_in[9];
  const float* cb2 = (const float*)d_in[10];
  const float* nw1 = (const float*)d_in[11];
  const float* nb1 = (const float*)d_in[12];
  const float* nw2 = (const float*)d_in[13];
  const float* nb2 = (const float*)d_in[14];
  const float* lng = (const float*)d_in[15];
  const float* lnb = (const float*)d_in[16];
  float* out = (float*)d_out;
  float* ws  = (float*)d_ws;
  unsigned short* wsU = (unsigned short*)d_ws;

  hipLaunchKernelGGL(k01_prep, dim3(721), dim3(256), 0, stream,
                     h, ew1, eb1, ew2, cw1, eb2, nw1, nw2, ws, wsU);
  hipLaunchKernelGGL(k3_edge, dim3(NNODE), dim3(256), 0, stream,
                     pos, vel, h, cb1, cw2, cb2, eb2,
                     nb1, nb2, lng, lnb, ws, out);
}